// Round 7
// baseline (131.195 us; speedup 1.0000x reference)
//
#include <hip/hip_runtime.h>
#include <stdint.h>

// Fused binary-morphology skeleton, one dispatch.
// Pack: float4 loads + nibble + shfl_xor OR-reduce, straight into LDS.
// Morph: separable rectangle erode/dilate, shrinking radii, TH=32 strips
// (512 blocks x 8 waves = 2 blocks/CU) so loads overlap barrier chains.

typedef unsigned long long u64;
typedef float vfloat4 __attribute__((ext_vector_type(4)));

#define WIDTH   1024
#define HEIGHT  1024
#define NIMG    16
#define WPR     16          // u64 words per image row
#define TH      32          // output rows per block
#define HALO    16
#define RRROWS  64          // region rows = TH + 2*HALO
#define PR      66          // padded rows (zero ring)
#define PW      18          // padded words (zero ring)
#define NTHR    512

// ---------------- bit-parallel separable helpers (LSB = leftmost pixel) -------
template <int CM>
__device__ __forceinline__ u64 hand(const u64* Ar, int w) {
    u64 c = Ar[w], res = ~0ULL;
    if (CM & 2) res &= c;
    if (CM & 1) res &= (c << 1) | (Ar[w - 1] >> 63);   // sample x-1
    if (CM & 4) res &= (c >> 1) | (Ar[w + 1] << 63);   // sample x+1
    return res;
}
template <int CM>
__device__ __forceinline__ u64 hor(const u64* Ar, int w) {
    u64 c = Ar[w], res = 0;
    if (CM & 2) res |= c;
    if (CM & 1) res |= (c >> 1) | (Ar[w + 1] << 63);   // sample x+1
    if (CM & 4) res |= (c << 1) | (Ar[w - 1] >> 63);   // sample x-1
    return res;
}
template <int RM>
__device__ __forceinline__ u64 vand(const u64 (*A)[PW], int r, int w) {
    u64 res = ~0ULL;
    if (RM & 1) res &= A[r - 1][w];
    if (RM & 2) res &= A[r][w];
    if (RM & 4) res &= A[r + 1][w];
    return res;
}
template <int RM>
__device__ __forceinline__ u64 vor(const u64 (*A)[PW], int r, int w) {
    u64 res = 0;
    if (RM & 1) res |= A[r + 1][w];
    if (RM & 2) res |= A[r][w];
    if (RM & 4) res |= A[r - 1][w];
    return res;
}

// Apply f(r,w) to all cells within row-radius R of the tile (tile = padded
// rows 17..17+TH-1), full width (padded words 1..16). Barrier afterwards.
template <int R, typename F>
__device__ __forceinline__ void forcells(F f) {
    for (int idx = threadIdx.x; idx < (TH + 2 * R) * WPR; idx += NTHR) {
        int r = 17 - R + (idx >> 4);
        int w = 1 + (idx & 15);
        f(r, w);
    }
    __syncthreads();
}

// One skeleton step: M = erode(B,S); O |= M; B &= ~dilate(M, reflect(S)).
template <int RM, int CM, int HR, int MR, int DHR, int BR, bool DIL>
__device__ __forceinline__ void morph_step(u64 (&B)[PR][PW], u64 (&T)[PR][PW],
                                           u64 (&M)[PR][PW], u64 (&O)[PR][PW]) {
    if (CM != 2 && RM != 2) {
        forcells<HR>([&](int r, int w) { T[r][w] = hand<CM>(B[r], w); });
        forcells<MR>([&](int r, int w) {
            u64 m = vand<RM>(T, r, w); M[r][w] = m; O[r][w] |= m;
        });
    } else if (CM == 2) {            // column-only kernel
        forcells<MR>([&](int r, int w) {
            u64 m = vand<RM>(B, r, w); M[r][w] = m; O[r][w] |= m;
        });
    } else {                         // row-only kernel
        forcells<MR>([&](int r, int w) {
            u64 m = hand<CM>(B[r], w); M[r][w] = m; O[r][w] |= m;
        });
    }
    if (DIL) {
        if (CM != 2 && RM != 2) {
            forcells<DHR>([&](int r, int w) { T[r][w] = hor<CM>(M[r], w); });
            forcells<BR>([&](int r, int w) { B[r][w] &= ~vor<RM>(T, r, w); });
        } else if (CM == 2) {
            forcells<BR>([&](int r, int w) { B[r][w] &= ~vor<RM>(M, r, w); });
        } else {
            forcells<BR>([&](int r, int w) { B[r][w] &= ~hor<CM>(M[r], w); });
        }
    }
}

// ---------------- fused: pack + 8-step morphology + isolated-point -----------
__global__ __launch_bounds__(NTHR) void skel_kernel(const float* __restrict__ x,
                                                    float* __restrict__ out) {
    __shared__ u64 B[PR][PW];
    __shared__ u64 T[PR][PW];
    __shared__ u64 M[PR][PW];
    __shared__ u64 O[PR][PW];
    int tid = threadIdx.x;
    int ty = blockIdx.x, img = blockIdx.y;

    // zero B, M, O (pads stay zero forever -> zero boundary); T needs no init
    {
        u64* bf = &B[0][0]; u64* mf = &M[0][0]; u64* of = &O[0][0];
        for (int i = tid; i < PR * PW; i += NTHR) { bf[i] = 0; mf[i] = 0; of[i] = 0; }
    }
    __syncthreads();

    // pack region rows ty*TH-16 .. ty*TH+TH+15 (clipped) straight into LDS:
    // float4 load -> nibble -> shfl_xor OR-reduce over 16-lane groups.
    {
        int wv = tid >> 6, lane = tid & 63;
        const float* ximg = x + (size_t)img * HEIGHT * WIDTH;
        for (int rr = wv; rr < RRROWS; rr += NTHR / 64) {   // 8 rows per wave
            int gy = ty * TH - HALO + rr;
            if (gy >= 0 && gy < HEIGHT) {
                const float* rbase = ximg + (size_t)gy * WIDTH;
                #pragma unroll
                for (int rnd = 0; rnd < 4; ++rnd) {          // 256 px per round
                    vfloat4 v = *(const vfloat4*)(rbase + rnd * 256 + lane * 4);
                    unsigned nib = (v.x > 0.5f ? 1u : 0u) | (v.y > 0.5f ? 2u : 0u)
                                 | (v.z > 0.5f ? 4u : 0u) | (v.w > 0.5f ? 8u : 0u);
                    u64 n = (u64)nib << (4 * (lane & 15));
                    n |= __shfl_xor(n, 1);
                    n |= __shfl_xor(n, 2);
                    n |= __shfl_xor(n, 4);
                    n |= __shfl_xor(n, 8);
                    if ((lane & 15) == 0) B[rr + 1][rnd * 4 + (lane >> 4) + 1] = n;
                }
            }
        }
    }
    __syncthreads();

    // 8 structuring elements as (rowmask, colmask) rectangles; radii shrink 2/step
    morph_step<7, 7, 16, 15, 15, 14, true >(B, T, M, O);  // all ones
    morph_step<7, 6, 14, 13, 13, 12, true >(B, T, M, O);  // cols {1,2}
    morph_step<3, 7, 12, 11, 11, 10, true >(B, T, M, O);  // rows {0,1}
    morph_step<6, 6, 10,  9,  9,  8, true >(B, T, M, O);  // rows {1,2} x cols {1,2}
    morph_step<7, 2,  8,  7,  7,  6, true >(B, T, M, O);  // col {1}
    morph_step<2, 7,  6,  5,  5,  4, true >(B, T, M, O);  // row {1}
    morph_step<3, 2,  4,  3,  3,  2, true >(B, T, M, O);  // col {1}, rows {0,1}
    morph_step<2, 3,  2,  1,  1,  0, false>(B, T, M, O);  // row {1}, cols {0,1}

    // isolated-point: 3x3 popcount of O == 1 via carry-save (ones, sticky twos)
    forcells<0>([&](int r, int w) {
        u64 ones = 0;
        u64 twos = 0;
        #pragma unroll
        for (int dr = -1; dr <= 1; ++dr) {
            const u64* Ar = O[r + dr];
            u64 c  = Ar[w];
            u64 wv = (c << 1) | (Ar[w - 1] >> 63);
            u64 ev = (c >> 1) | (Ar[w + 1] << 63);
            twos |= ones & wv; ones ^= wv;
            twos |= ones & c;  ones ^= c;
            twos |= ones & ev; ones ^= ev;
        }
        T[r][w] = ones & ~twos;
    });

    // write float output, float4 nontemporal, coalesced
    float* obase = out + ((size_t)img * HEIGHT + (size_t)ty * TH) * WIDTH;
    for (int idx = tid; idx < TH * (WIDTH / 4); idx += NTHR) {
        int row = idx >> 8;           // 256 float4 groups per row
        int q   = idx & 255;
        u64 word = T[17 + row][1 + (q >> 4)];
        int b = (q & 15) * 4;
        vfloat4 v;
        v.x = (float)((word >> (b + 0)) & 1ULL);
        v.y = (float)((word >> (b + 1)) & 1ULL);
        v.z = (float)((word >> (b + 2)) & 1ULL);
        v.w = (float)((word >> (b + 3)) & 1ULL);
        __builtin_nontemporal_store(v, (vfloat4*)(obase + (size_t)row * WIDTH + q * 4));
    }
}

extern "C" void kernel_launch(void* const* d_in, const int* in_sizes, int n_in,
                              void* d_out, int out_size, void* d_ws, size_t ws_size,
                              hipStream_t stream) {
    const float* x = (const float*)d_in[0];
    float* out = (float*)d_out;
    hipLaunchKernelGGL(skel_kernel, dim3(HEIGHT / TH, NIMG), dim3(NTHR), 0, stream,
                       x, out);
}

// Round 8
// 116.614 us; speedup vs baseline: 1.1250x; 1.1250x over previous
//
#include <hip/hip_runtime.h>
#include <stdint.h>

// Two-kernel binary-morphology skeleton.
// Pack: float4 loads + nibble + shfl_xor OR-reduce -> 64px/word bitmask (R6 proven).
// Morph: wave-autonomous REGISTER morphology — lane i holds rows 2i,2i+1 x
// 3 u64 words (center output word + halo word each side; horizontal reach
// is only +/-17px). Vertical neighbors via __shfl lane+/-1. Zero barriers in
// the 8-step chain; one barrier before the LDS-staged coalesced expand.

typedef unsigned long long u64;
typedef float vfloat4 __attribute__((ext_vector_type(4)));

#define WIDTH   1024
#define HEIGHT  1024
#define NIMG    16
#define WPR     16          // u64 words per image row
#define RPL     2           // rows per lane
#define VROWS   128         // rows covered per wave = 64*RPL
#define HALO    17          // 8 steps x (erode+dilate) + iso conv
#define BVALID  94          // VROWS - 2*HALO
#define NBANDS  11          // ceil(1024/94)
#define PACK_ROWS 4

// ---------------- phase 1: binarize + bit-pack, float4 + shfl assembly -------
__global__ __launch_bounds__(256) void pack_kernel(const float* __restrict__ x,
                                                   u64* __restrict__ packed) {
    int wv = threadIdx.x >> 6, lane = threadIdx.x & 63;
    int row = blockIdx.x * PACK_ROWS + wv;        // one image row per wave
    const float* rbase = x + (size_t)row * WIDTH;
    u64* pbase = packed + (size_t)row * WPR;
    #pragma unroll
    for (int rnd = 0; rnd < 4; ++rnd) {           // 256 px per round
        vfloat4 v = *(const vfloat4*)(rbase + rnd * 256 + lane * 4);
        unsigned nib = (v.x > 0.5f ? 1u : 0u) | (v.y > 0.5f ? 2u : 0u)
                     | (v.z > 0.5f ? 4u : 0u) | (v.w > 0.5f ? 8u : 0u);
        u64 n = (u64)nib << (4 * (lane & 15));
        n |= __shfl_xor(n, 1);                    // OR-reduce within 16-lane
        n |= __shfl_xor(n, 2);                    // groups: group g holds
        n |= __shfl_xor(n, 4);                    // px 256*rnd+64g..+63
        n |= __shfl_xor(n, 8);
        if ((lane & 15) == 0) pbase[rnd * 4 + (lane >> 4)] = n;
    }
}

// ---------------- wave-edge shuffles (zero beyond wave = halo/zero-pad) -------
__device__ __forceinline__ u64 sh_up(u64 x, int lane) {
    u64 t = __shfl(x, lane - 1);
    return lane == 0 ? 0ULL : t;
}
__device__ __forceinline__ u64 sh_dn(u64 x, int lane) {
    u64 t = __shfl(x, lane + 1);
    return lane == 63 ? 0ULL : t;
}

// One skeleton step, fully in registers. Bit (LSB) = leftmost pixel.
// hand: CM&1 -> sample x-1 = (c<<1)|(left>>63); vand: RM&1 -> row above.
// Dilate uses reflected kernel (offsets negated). Proven mapping from R6.
template <int RM, int CM, bool DIL>
__device__ __forceinline__ void mstep(u64 (&B)[RPL][3], u64 (&O)[RPL][3], int lane) {
    u64 T[RPL][3], M[RPL][3];
    // horizontal erode
    #pragma unroll
    for (int s = 0; s < RPL; ++s) {
        #pragma unroll
        for (int j = 0; j < 3; ++j) {
            u64 c = B[s][j], res = ~0ULL;
            if (CM & 2) res &= c;
            if (CM & 1) res &= (c << 1) | ((j > 0 ? B[s][j - 1] : 0ULL) >> 63);
            if (CM & 4) res &= (c >> 1) | ((j < 2 ? B[s][j + 1] : 0ULL) << 63);
            T[s][j] = res;
        }
    }
    // vertical erode -> M, O
    #pragma unroll
    for (int j = 0; j < 3; ++j) {
        u64 up = sh_up(T[RPL - 1][j], lane);
        u64 dn = sh_dn(T[0][j], lane);
        #pragma unroll
        for (int s = 0; s < RPL; ++s) {
            u64 res = ~0ULL;
            if (RM & 2) res &= T[s][j];
            if (RM & 1) res &= (s > 0 ? T[s - 1][j] : up);
            if (RM & 4) res &= (s < RPL - 1 ? T[s + 1][j] : dn);
            M[s][j] = res;
            O[s][j] |= res;
        }
    }
    if (DIL) {
        // horizontal dilate (reflected)
        #pragma unroll
        for (int s = 0; s < RPL; ++s) {
            #pragma unroll
            for (int j = 0; j < 3; ++j) {
                u64 c = M[s][j], res = 0;
                if (CM & 2) res |= c;
                if (CM & 1) res |= (c >> 1) | ((j < 2 ? M[s][j + 1] : 0ULL) << 63);
                if (CM & 4) res |= (c << 1) | ((j > 0 ? M[s][j - 1] : 0ULL) >> 63);
                T[s][j] = res;
            }
        }
        // vertical dilate (reflected), subtract from B
        #pragma unroll
        for (int j = 0; j < 3; ++j) {
            u64 up = sh_up(T[RPL - 1][j], lane);
            u64 dn = sh_dn(T[0][j], lane);
            #pragma unroll
            for (int s = 0; s < RPL; ++s) {
                u64 res = 0;
                if (RM & 2) res |= T[s][j];
                if (RM & 1) res |= (s < RPL - 1 ? T[s + 1][j] : dn);
                if (RM & 4) res |= (s > 0 ? T[s - 1][j] : up);
                B[s][j] &= ~res;
            }
        }
    }
}

// ---------------- phase 2: register morphology + isolated-point + expand -----
__global__ __launch_bounds__(256) void regmorph_kernel(const u64* __restrict__ packed,
                                                       float* __restrict__ out) {
    __shared__ u64 stage[4][BVALID + 2];
    int lane = threadIdx.x & 63;
    int wv = threadIdx.x >> 6;
    int W = blockIdx.x * 4 + wv;                  // flat wave id, 0..2815
    int img  = W / (WPR * NBANDS);
    int rem  = W % (WPR * NBANDS);
    int wcol = rem / NBANDS;
    int band = rem % NBANDS;
    int bstart = band * BVALID - HALO;            // global row of v=0

    // load 2 rows x 3 words per lane, zero outside image (zero-pad semantics)
    const u64* pimg = packed + (size_t)img * HEIGHT * WPR;
    u64 B[RPL][3], O[RPL][3];
    #pragma unroll
    for (int s = 0; s < RPL; ++s) {
        int g = bstart + lane * RPL + s;
        bool rok = (g >= 0 && g < HEIGHT);
        #pragma unroll
        for (int j = 0; j < 3; ++j) {
            int wi = wcol - 1 + j;
            B[s][j] = (rok && wi >= 0 && wi < WPR) ? pimg[(size_t)g * WPR + wi] : 0ULL;
            O[s][j] = 0ULL;
        }
    }

    // 8 structuring elements as (rowmask, colmask) rectangles
    mstep<7, 7, true >(B, O, lane);   // all ones
    mstep<7, 6, true >(B, O, lane);   // cols {1,2}
    mstep<3, 7, true >(B, O, lane);   // rows {0,1}
    mstep<6, 6, true >(B, O, lane);   // rows {1,2} x cols {1,2}
    mstep<7, 2, true >(B, O, lane);   // col {1}
    mstep<2, 7, true >(B, O, lane);   // row {1}
    mstep<3, 2, true >(B, O, lane);   // col {1}, rows {0,1}
    mstep<2, 3, false>(B, O, lane);   // row {1}, cols {0,1}; B unused after

    // isolated-point: 3x3 popcount of O == 1, center word only (carry-save)
    u64 Wn[RPL], Cn[RPL], En[RPL], res[RPL];
    #pragma unroll
    for (int s = 0; s < RPL; ++s) {
        Cn[s] = O[s][1];
        Wn[s] = (O[s][1] << 1) | (O[s][0] >> 63);
        En[s] = (O[s][1] >> 1) | (O[s][2] << 63);
    }
    u64 upW = sh_up(Wn[RPL - 1], lane), upC = sh_up(Cn[RPL - 1], lane),
        upE = sh_up(En[RPL - 1], lane);
    u64 dnW = sh_dn(Wn[0], lane), dnC = sh_dn(Cn[0], lane), dnE = sh_dn(En[0], lane);
    #pragma unroll
    for (int s = 0; s < RPL; ++s) {
        u64 ones = 0, twos = 0;
        auto acc = [&](u64 v) { twos |= ones & v; ones ^= v; };
        acc(s > 0 ? Wn[s - 1] : upW);
        acc(s > 0 ? Cn[s - 1] : upC);
        acc(s > 0 ? En[s - 1] : upE);
        acc(Wn[s]); acc(Cn[s]); acc(En[s]);
        acc(s < RPL - 1 ? Wn[s + 1] : dnW);
        acc(s < RPL - 1 ? Cn[s + 1] : dnC);
        acc(s < RPL - 1 ? En[s + 1] : dnE);
        res[s] = ones & ~twos;
    }

    // stage valid rows (v in [HALO, HALO+BVALID)) into this wave's LDS slice
    #pragma unroll
    for (int s = 0; s < RPL; ++s) {
        int v = lane * RPL + s;
        if (v >= HALO && v < HALO + BVALID) stage[wv][v - HALO] = res[s];
    }
    __syncthreads();   // uniform across all 4 waves

    // expand to f32, coalesced: per instr 4 rows x 16 lanes x 16 B (full lines)
    int gbase = band * BVALID;
    float* obase = out + (size_t)img * HEIGHT * WIDTH + wcol * 64 + (lane & 15) * 4;
    for (int it = 0; it < (BVALID + 3) / 4; ++it) {
        int t = it * 4 + (lane >> 4);
        int g = gbase + t;
        if (t < BVALID && g < HEIGHT) {
            u64 word = stage[wv][t];
            unsigned nib = (unsigned)(word >> ((lane & 15) * 4)) & 15u;
            vfloat4 v4;
            v4.x = (nib & 1) ? 1.f : 0.f;
            v4.y = (nib & 2) ? 1.f : 0.f;
            v4.z = (nib & 4) ? 1.f : 0.f;
            v4.w = (nib & 8) ? 1.f : 0.f;
            __builtin_nontemporal_store(v4, (vfloat4*)(obase + (size_t)g * WIDTH));
        }
    }
}

extern "C" void kernel_launch(void* const* d_in, const int* in_sizes, int n_in,
                              void* d_out, int out_size, void* d_ws, size_t ws_size,
                              hipStream_t stream) {
    const float* x = (const float*)d_in[0];
    float* out = (float*)d_out;
    u64* packed = (u64*)d_ws;   // NIMG*HEIGHT*WPR*8 = 2 MiB used

    hipLaunchKernelGGL(pack_kernel, dim3(NIMG * HEIGHT / PACK_ROWS), dim3(256), 0,
                       stream, x, packed);
    hipLaunchKernelGGL(regmorph_kernel,
                       dim3(NIMG * WPR * NBANDS / 4), dim3(256), 0, stream,
                       packed, out);
}